// Round 5
// baseline (125.667 us; speedup 1.0000x reference)
//
#include <hip/hip_runtime.h>

typedef unsigned int u32;
typedef unsigned short u16;
typedef _Float16 f16;
typedef __attribute__((ext_vector_type(2))) _Float16 f16x2;
typedef __attribute__((ext_vector_type(8))) _Float16 f16x8;

__device__ __forceinline__ float bf16f(u16 v) { u32 x = ((u32)v) << 16; return __builtin_bit_cast(float, x); }
__device__ __forceinline__ u16 f2bf(float f) {  // round-to-nearest-even (round-2-proven)
    u32 x = __builtin_bit_cast(u32, f);
    return (u16)((x + 0x7fffu + ((x >> 16) & 1u)) >> 16);
}

// ---------------------------------------------------------------------------
// k_prep: featp[row][col] = f16(feat[row][col]) for col<25, else 0. (row = 64B)
// ---------------------------------------------------------------------------
__global__ __launch_bounds__(256) void k_prep(const float* __restrict__ feat,
                                              f16* __restrict__ featp, int N) {
    int t = blockIdx.x * 256 + threadIdx.x;
    int row = t >> 5, col = t & 31;
    if (row >= N) return;
    featp[(size_t)row * 32 + col] = (col < 25) ? (f16)feat[(size_t)row * 25 + col] : (f16)0.f;
}

// ---------------------------------------------------------------------------
// k_gather: ONE THREAD per (relation,node) pair t = r*N+node.
//   meansum[t][0:32] = f16( sum_{k<32} featp[adj[r,node,k], :] )   (f32 accum)
// Each VMEM instruction: 64 lanes x 16B = 1KB of gathered rows. No cross-lane.
// ---------------------------------------------------------------------------
__global__ __launch_bounds__(256) void k_gather(const f16* __restrict__ featp,
                                                const int* __restrict__ adj,
                                                f16* __restrict__ meansum, int N) {
    int t = blockIdx.x * 256 + threadIdx.x;
    if (t >= 3 * N) return;
    int r = (t >= 2 * N) ? 2 : ((t >= N) ? 1 : 0);
    int node = t - r * N;
    const int4* arow = (const int4*)(adj + ((size_t)r * N + node) * 32);

    float acc[32];
#pragma unroll
    for (int j = 0; j < 32; ++j) acc[j] = 0.f;

#pragma unroll
    for (int k4 = 0; k4 < 8; ++k4) {
        int4 nb4 = arow[k4];
        int nbs[4] = {nb4.x, nb4.y, nb4.z, nb4.w};
#pragma unroll
        for (int q = 0; q < 4; ++q) {
            const f16x8* rowp = (const f16x8*)(featp + (size_t)nbs[q] * 32);
#pragma unroll
            for (int j = 0; j < 4; ++j) {
                f16x8 hv = rowp[j];
#pragma unroll
                for (int jj = 0; jj < 8; ++jj) acc[j * 8 + jj] += (float)hv[jj];
            }
        }
    }

    f16x8* outp = (f16x8*)(meansum + (size_t)t * 32);
#pragma unroll
    for (int j = 0; j < 4; ++j) {
        f16x8 o;
#pragma unroll
        for (int jj = 0; jj < 8; ++jj) o[jj] = (f16)acc[j * 8 + jj];
        outp[j] = o;
    }
}

// ---------------------------------------------------------------------------
// k_apply: wave per node — EXACT round-2 k_layer1 structure/arithmetic, with
// the gather replaced by one coalesced meansum load, and self = feat[i]·wcol.
//   w1[i,c]    = bf16( sum_r softmax1T[c,r]*mean_r[c] )
//   w1[i,64+c] = bf16( self[c] - sum_r softmax1B[c,r]*mean_r[c] )
// ---------------------------------------------------------------------------
__global__ __launch_bounds__(256) void k_apply(const f16* __restrict__ meansum,
                                               const float* __restrict__ feat,
                                               const float* __restrict__ Wmlp,
                                               const float* __restrict__ alpha1,
                                               u16* __restrict__ w1, int N) {
    int wave = threadIdx.x >> 6;
    int lane = threadIdx.x & 63;
    int i = blockIdx.x * 4 + wave;
    if (i >= N) return;
    int c = lane & 15;   // column-pair index: cols 2c, 2c+1

    // register-cache W column: wcol[k] = W[k][lane]   (round-2-identical)
    float wcol[25];
#pragma unroll
    for (int k = 0; k < 25; ++k) wcol[k] = Wmlp[k * 64 + lane];

    // load neighbor sums: lane c holds cols 2c,2c+1 of the 32-row sum (all 4
    // 16-lane groups redundant — identical semantics to round 2 post-reduce)
    const u32* ms32 = (const u32*)meansum;
    float a0[3], a1[3];
#pragma unroll
    for (int r = 0; r < 3; ++r) {
        u32 v = ms32[((size_t)r * N + i) * 16 + c];
        f16x2 h = __builtin_bit_cast(f16x2, v);
        a0[r] = (float)h[0];
        a1[r] = (float)h[1];
    }

    // mean_r[lane] = (1/32) * sum_k meanfeat_r[k] * W[k][lane]  (round-2 verbatim)
    float mean[3];
#pragma unroll
    for (int r = 0; r < 3; ++r) {
        float acc = 0.f;
#pragma unroll
        for (int k = 0; k < 25; ++k) {
            int src = (k & 1) ? __builtin_bit_cast(int, a1[r]) : __builtin_bit_cast(int, a0[r]);
            float mf = __builtin_bit_cast(float, __builtin_amdgcn_readlane(src, k >> 1));
            acc += mf * wcol[k];
        }
        mean[r] = acc * (1.f / 32.f);
    }

    // self = h0[i][lane] computed on the fly (feat row is wave-uniform)
    const float* frow = feat + (size_t)i * 25;
    float self = 0.f;
#pragma unroll
    for (int k = 0; k < 25; ++k) self += frow[k] * wcol[k];

    // per-column softmax over 3 relations (round-2 verbatim)
    float et[3], eb[3], st = 0.f, sb = 0.f;
#pragma unroll
    for (int r = 0; r < 3; ++r) {
        et[r] = __expf(alpha1[lane * 3 + r]);        st += et[r];
        eb[r] = __expf(alpha1[(64 + lane) * 3 + r]); sb += eb[r];
    }
    float top = 0.f, bot = 0.f;
#pragma unroll
    for (int r = 0; r < 3; ++r) { top += et[r] * mean[r]; bot += eb[r] * mean[r]; }
    top /= st;
    bot /= sb;

    w1[(size_t)i * 128 + lane]      = f2bf(top);
    w1[(size_t)i * 128 + 64 + lane] = f2bf(self - bot);
}

// ---------------------------------------------------------------------------
// k_layer2: round-2 VERBATIM (passed), except t0 = h0[i][t] is recomputed
// on the fly from feat·W. One 128-thread block per batch node.
// ---------------------------------------------------------------------------
__global__ __launch_bounds__(128) void k_layer2(const float* __restrict__ feat,
                                                const float* __restrict__ Wmlp,
                                                const u16* __restrict__ w1h,
                                                const float* __restrict__ alpha2,
                                                const float* __restrict__ lw,
                                                const float* __restrict__ prior,
                                                const int* __restrict__ adj,
                                                const int* __restrict__ nodes,
                                                float* __restrict__ out, int N) {
    __shared__ int s_idx[96];
    __shared__ float s_red[4];
    int b = blockIdx.x;
    int i = nodes[b];
    int t = threadIdx.x;

    if (t < 96) {
        int r = t >> 5, k = t & 31;
        s_idx[t] = adj[((size_t)r * N + i) * 32 + k];
    }
    __syncthreads();

    float mean[3];
#pragma unroll
    for (int r = 0; r < 3; ++r) {
        float acc = 0.f;
#pragma unroll
        for (int k = 0; k < 32; ++k)
            acc += bf16f(w1h[(size_t)s_idx[r * 32 + k] * 128 + t]);  // coalesced
        mean[r] = acc * (1.f / 32.f);
    }

    float et[3], eb[3], st = 0.f, sb = 0.f;
#pragma unroll
    for (int r = 0; r < 3; ++r) {
        et[r] = __expf(alpha2[t * 3 + r]);         st += et[r];
        eb[r] = __expf(alpha2[(128 + t) * 3 + r]); sb += eb[r];
    }
    float t2 = 0.f, wb = 0.f;
#pragma unroll
    for (int r = 0; r < 3; ++r) { t2 += et[r] * mean[r]; wb += eb[r] * mean[r]; }
    t2 /= st;
    wb /= sb;

    float t1 = bf16f(w1h[(size_t)i * 128 + t]);
    float t3 = t1 - wb;

    float p0 = t1 * lw[(64 + t) * 2 + 0] + t2 * lw[(192 + t) * 2 + 0] + t3 * lw[(320 + t) * 2 + 0];
    float p1 = t1 * lw[(64 + t) * 2 + 1] + t2 * lw[(192 + t) * 2 + 1] + t3 * lw[(320 + t) * 2 + 1];
    if (t < 64) {
        float t0 = 0.f;
#pragma unroll
        for (int k = 0; k < 25; ++k) t0 += feat[(size_t)i * 25 + k] * Wmlp[k * 64 + t];
        p0 += t0 * lw[t * 2 + 0];
        p1 += t0 * lw[t * 2 + 1];
    }

#pragma unroll
    for (int off = 32; off > 0; off >>= 1) {
        p0 += __shfl_down(p0, off, 64);
        p1 += __shfl_down(p1, off, 64);
    }
    int wv = t >> 6, lane = t & 63;
    if (lane == 0) { s_red[wv * 2 + 0] = p0; s_red[wv * 2 + 1] = p1; }
    __syncthreads();
    if (t == 0) {
        out[b * 2 + 0] = s_red[0] + s_red[2] + __logf(prior[0]);
        out[b * 2 + 1] = s_red[1] + s_red[3] + __logf(prior[1]);
    }
}

extern "C" void kernel_launch(void* const* d_in, const int* in_sizes, int n_in,
                              void* d_out, int out_size, void* d_ws, size_t ws_size,
                              hipStream_t stream) {
    const float* feat   = (const float*)d_in[0];  // [N,25]
    const float* Wmlp   = (const float*)d_in[1];  // [25,64]
    const float* alpha1 = (const float*)d_in[2];  // [128,3]
    const float* alpha2 = (const float*)d_in[3];  // [256,3]
    const float* lw     = (const float*)d_in[4];  // [448,2]
    const float* prior  = (const float*)d_in[5];  // [2]
    const int*   adj    = (const int*)d_in[6];    // [3,N,32]
    const int*   nodes  = (const int*)d_in[7];    // [B]
    float* out = (float*)d_out;

    int N = in_sizes[0] / 25;   // 50000
    int B = in_sizes[7];        // 1024

    // ws: featp 3.2MB | meansum 9.6MB | w1 12.8MB  = 25.6MB (< 28.8MB proven)
    f16* featp   = (f16*)d_ws;                       // [N][32]  f16
    f16* meansum = featp + (size_t)N * 32;           // [3N][32] f16
    u16* w1      = (u16*)(meansum + (size_t)3 * N * 32); // [N][128] bf16

    k_prep  <<<(N * 32 + 255) / 256, 256, 0, stream>>>(feat, featp, N);
    k_gather<<<(3 * N + 255) / 256,  256, 0, stream>>>(featp, adj, meansum, N);
    k_apply <<<(N + 3) / 4,          256, 0, stream>>>(meansum, feat, Wmlp, alpha1, w1, N);
    k_layer2<<<B,                    128, 0, stream>>>(feat, Wmlp, w1, alpha2, lw, prior, adj, nodes, out, N);
}

// Round 7
// 61.694 us; speedup vs baseline: 2.0369x; 2.0369x over previous
//
#include <hip/hip_runtime.h>

typedef unsigned int u32;
typedef unsigned short u16;

__device__ __forceinline__ float bf16_lo(u32 u) { u32 x = u << 16; return __builtin_bit_cast(float, x); }
__device__ __forceinline__ float bf16_hi(u32 u) { u32 x = u & 0xffff0000u; return __builtin_bit_cast(float, x); }
__device__ __forceinline__ float bf16f(u16 v) { u32 x = ((u32)v) << 16; return __builtin_bit_cast(float, x); }
__device__ __forceinline__ u16 f2bf(float f) {  // round-to-nearest-even (round-2-proven)
    u32 x = __builtin_bit_cast(u32, f);
    return (u16)((x + 0x7fffu + ((x >> 16) & 1u)) >> 16);
}

// ---------------------------------------------------------------------------
// k_prep: featp[row][col] = bf16(feat[row][col]) for col<25, else 0 (32-col pad)
// (round-5 structure, round-2 bf16 encoding — both proven)
// ---------------------------------------------------------------------------
__global__ __launch_bounds__(256) void k_prep(const float* __restrict__ feat,
                                              u16* __restrict__ featp, int N) {
    int t = blockIdx.x * 256 + threadIdx.x;
    int row = t >> 5, col = t & 31;
    if (row >= N) return;
    featp[(size_t)row * 32 + col] = (col < 25) ? f2bf(feat[(size_t)row * 25 + col]) : (u16)0;
}

// ---------------------------------------------------------------------------
// k_layer1: ROUND-2 k_layer1 VERBATIM (passed end-to-end at 48us), with one
// proven diff: self = feat[i]·wcol recomputed (round-5 k_apply snippet)
// instead of reading a precomputed h0 buffer.
// One wave per node; 16-lane group g handles neighbor slot it*4+g; lane&15 =
// column pair of featp; readlane-broadcast matmul; softmax(alpha1) fusion.
// ---------------------------------------------------------------------------
__global__ __launch_bounds__(256) void k_layer1(const float* __restrict__ feat,
                                                const u16* __restrict__ featp,
                                                const float* __restrict__ Wmlp,
                                                const float* __restrict__ alpha1,
                                                const int* __restrict__ adj,
                                                u16* __restrict__ w1h, int N) {
    int wave = threadIdx.x >> 6;
    int lane = threadIdx.x & 63;
    int i = blockIdx.x * 4 + wave;
    if (i >= N) return;
    int g = lane >> 4;    // neighbor subgroup 0..3
    int c = lane & 15;    // column-pair index: cols 2c, 2c+1

    // register-cache W column: wcol[k] = W[k][lane]
    float wcol[25];
#pragma unroll
    for (int k = 0; k < 25; ++k) wcol[k] = Wmlp[k * 64 + lane];

    const u32* fp = (const u32*)featp;  // 16 u32 per padded row

    float a0[3], a1[3];
#pragma unroll
    for (int r = 0; r < 3; ++r) {
        const int* arow = adj + ((size_t)r * N + i) * 32;
        float s0 = 0.f, s1 = 0.f;
#pragma unroll
        for (int it = 0; it < 8; ++it) {
            int nb = arow[it * 4 + g];          // 16 lanes share addr -> broadcast
            u32 u = fp[nb * 16 + c];            // 64B per group, coalesced
            s0 += bf16_lo(u);
            s1 += bf16_hi(u);
        }
        // reduce across the 4 subgroups (lanes with equal lane&15)
        s0 += __shfl_xor(s0, 16, 64); s0 += __shfl_xor(s0, 32, 64);
        s1 += __shfl_xor(s1, 16, 64); s1 += __shfl_xor(s1, 32, 64);
        a0[r] = s0; a1[r] = s1;
    }

    // mean_r[lane] = (1/32) * sum_k meanfeat_r[k] * W[k][lane]
    float mean[3];
#pragma unroll
    for (int r = 0; r < 3; ++r) {
        float acc = 0.f;
#pragma unroll
        for (int k = 0; k < 25; ++k) {
            int src = (k & 1) ? __builtin_bit_cast(int, a1[r]) : __builtin_bit_cast(int, a0[r]);
            float mf = __builtin_bit_cast(float, __builtin_amdgcn_readlane(src, k >> 1));
            acc += mf * wcol[k];
        }
        mean[r] = acc * (1.f / 32.f);
    }

    // self = h0[i][lane] computed on the fly (round-5-proven snippet)
    const float* frow = feat + (size_t)i * 25;
    float self = 0.f;
#pragma unroll
    for (int k = 0; k < 25; ++k) self += frow[k] * wcol[k];

    // per-column softmax over 3 relations
    float et[3], eb[3], st = 0.f, sb = 0.f;
#pragma unroll
    for (int r = 0; r < 3; ++r) {
        et[r] = __expf(alpha1[lane * 3 + r]);        st += et[r];
        eb[r] = __expf(alpha1[(64 + lane) * 3 + r]); sb += eb[r];
    }
    float top = 0.f, bot = 0.f;
#pragma unroll
    for (int r = 0; r < 3; ++r) { top += et[r] * mean[r]; bot += eb[r] * mean[r]; }
    top /= st;
    bot /= sb;

    w1h[(size_t)i * 128 + lane]      = f2bf(top);
    w1h[(size_t)i * 128 + 64 + lane] = f2bf(self - bot);
}

// ---------------------------------------------------------------------------
// k_layer2: round-5 VERBATIM (passed).
// ---------------------------------------------------------------------------
__global__ __launch_bounds__(128) void k_layer2(const float* __restrict__ feat,
                                                const float* __restrict__ Wmlp,
                                                const u16* __restrict__ w1h,
                                                const float* __restrict__ alpha2,
                                                const float* __restrict__ lw,
                                                const float* __restrict__ prior,
                                                const int* __restrict__ adj,
                                                const int* __restrict__ nodes,
                                                float* __restrict__ out, int N) {
    __shared__ int s_idx[96];
    __shared__ float s_red[4];
    int b = blockIdx.x;
    int i = nodes[b];
    int t = threadIdx.x;

    if (t < 96) {
        int r = t >> 5, k = t & 31;
        s_idx[t] = adj[((size_t)r * N + i) * 32 + k];
    }
    __syncthreads();

    float mean[3];
#pragma unroll
    for (int r = 0; r < 3; ++r) {
        float acc = 0.f;
#pragma unroll
        for (int k = 0; k < 32; ++k)
            acc += bf16f(w1h[(size_t)s_idx[r * 32 + k] * 128 + t]);  // coalesced
        mean[r] = acc * (1.f / 32.f);
    }

    float et[3], eb[3], st = 0.f, sb = 0.f;
#pragma unroll
    for (int r = 0; r < 3; ++r) {
        et[r] = __expf(alpha2[t * 3 + r]);         st += et[r];
        eb[r] = __expf(alpha2[(128 + t) * 3 + r]); sb += eb[r];
    }
    float t2 = 0.f, wb = 0.f;
#pragma unroll
    for (int r = 0; r < 3; ++r) { t2 += et[r] * mean[r]; wb += eb[r] * mean[r]; }
    t2 /= st;
    wb /= sb;

    float t1 = bf16f(w1h[(size_t)i * 128 + t]);
    float t3 = t1 - wb;

    float p0 = t1 * lw[(64 + t) * 2 + 0] + t2 * lw[(192 + t) * 2 + 0] + t3 * lw[(320 + t) * 2 + 0];
    float p1 = t1 * lw[(64 + t) * 2 + 1] + t2 * lw[(192 + t) * 2 + 1] + t3 * lw[(320 + t) * 2 + 1];
    if (t < 64) {
        float t0 = 0.f;
#pragma unroll
        for (int k = 0; k < 25; ++k) t0 += feat[(size_t)i * 25 + k] * Wmlp[k * 64 + t];
        p0 += t0 * lw[t * 2 + 0];
        p1 += t0 * lw[t * 2 + 1];
    }

#pragma unroll
    for (int off = 32; off > 0; off >>= 1) {
        p0 += __shfl_down(p0, off, 64);
        p1 += __shfl_down(p1, off, 64);
    }
    int wv = t >> 6, lane = t & 63;
    if (lane == 0) { s_red[wv * 2 + 0] = p0; s_red[wv * 2 + 1] = p1; }
    __syncthreads();
    if (t == 0) {
        out[b * 2 + 0] = s_red[0] + s_red[2] + __logf(prior[0]);
        out[b * 2 + 1] = s_red[1] + s_red[3] + __logf(prior[1]);
    }
}

extern "C" void kernel_launch(void* const* d_in, const int* in_sizes, int n_in,
                              void* d_out, int out_size, void* d_ws, size_t ws_size,
                              hipStream_t stream) {
    const float* feat   = (const float*)d_in[0];  // [N,25]
    const float* Wmlp   = (const float*)d_in[1];  // [25,64]
    const float* alpha1 = (const float*)d_in[2];  // [128,3]
    const float* alpha2 = (const float*)d_in[3];  // [256,3]
    const float* lw     = (const float*)d_in[4];  // [448,2]
    const float* prior  = (const float*)d_in[5];  // [2]
    const int*   adj    = (const int*)d_in[6];    // [3,N,32]
    const int*   nodes  = (const int*)d_in[7];    // [B]
    float* out = (float*)d_out;

    int N = in_sizes[0] / 25;   // 50000
    int B = in_sizes[7];        // 1024

    // ws: featp bf16 [N][32] 3.2MB | w1 bf16 [N][128] 12.8MB = 16MB (< 28.8 proven)
    u16* featp = (u16*)d_ws;
    u16* w1    = featp + (size_t)N * 32;

    k_prep  <<<(N * 32 + 255) / 256, 256, 0, stream>>>(feat, featp, N);
    k_layer1<<<(N + 3) / 4,          256, 0, stream>>>(feat, featp, Wmlp, alpha1, adj, w1, N);
    k_layer2<<<B,                    128, 0, stream>>>(feat, Wmlp, w1, alpha2, lw, prior, adj, nodes, out, N);
}